// Round 7
// baseline (393.520 us; speedup 1.0000x reference)
//
#include <hip/hip_runtime.h>
#include <stdint.h>

#define BATCH   8
#define NPTS    8192
#define SCH     1024
#define KNN     32
#define TOPC    5
#define MAXIT   16
#define NCELL   4096     // 16^3 morton cells
#define NGRP    128      // groups of 64 per batch

typedef unsigned long long ull;
typedef float vf2 __attribute__((ext_vector_type(2)));
typedef float vf4 __attribute__((ext_vector_type(4)));

// sentinel: unpacks to +inf d2, never enters top-32
#define SENTKEY ((((ull)0x7F800000u) << 13) | 0x1FFFull)

// ---------------------------------------------------------------------------
// Exact d2: separate mul/add roundings (no FMA), order ((dx2+dy2)+dz2) = numpy.
// ---------------------------------------------------------------------------
__device__ __forceinline__ float d2_exact(vf4 q, vf4 p) {
#pragma clang fp contract(off)
    vf2 d = q.xy - p.xy;
    vf2 s = d * d;
    float dz = q.z - p.z;
    float sz = dz * dz;
    return (s.x + s.y) + sz;
}

__device__ __forceinline__ void insert_top4(ull key, ull& k0, ull& k1, ull& k2,
                                            ull& k3, float& th) {
    if (key < k3) {
        k3 = key;
        { bool c = k3 < k2; ull mn = c ? k3 : k2, mx = c ? k2 : k3; k2 = mn; k3 = mx; }
        { bool c = k2 < k1; ull mn = c ? k2 : k1, mx = c ? k1 : k2; k1 = mn; k2 = mx; }
        { bool c = k1 < k0; ull mn = c ? k1 : k0, mx = c ? k0 : k1; k0 = mn; k1 = mx; }
        th = __uint_as_float((uint32_t)(k3 >> 13));
    }
}

__device__ __forceinline__ ull wave_min_u64(ull k) {
#pragma unroll
    for (int off = 32; off; off >>= 1) {
        ull o = (ull)__shfl_xor((unsigned long long)k, off, 64);
        k = o < k ? o : k;
    }
    return k;
}

// conservative (under-estimated) squared min distance from q to group bbox
__device__ __forceinline__ float bbox_mind2(vf4 q, vf4 c, vf4 h) {
    float dx = fmaxf(fabsf(q.x - c.x) - h.x, 0.f);
    float dy = fmaxf(fabsf(q.y - c.y) - h.y, 0.f);
    float dz = fmaxf(fabsf(q.z - c.z) - h.z, 0.f);
    return (dx * dx + dy * dy + dz * dz) * 0.9999f;
}

// morton cell id from point (16^3 over [-4,4], clamped)
__device__ __forceinline__ int cell_of(float x, float y, float z) {
    int cxi = min(15, max(0, (int)floorf((x + 4.0f) * 2.0f)));
    int cyi = min(15, max(0, (int)floorf((y + 4.0f) * 2.0f)));
    int czi = min(15, max(0, (int)floorf((z + 4.0f) * 2.0f)));
    uint32_t sx = (cxi & 1) | ((cxi & 2) << 2) | ((cxi & 4) << 4) | ((cxi & 8) << 6);
    uint32_t sy = (cyi & 1) | ((cyi & 2) << 2) | ((cyi & 4) << 4) | ((cyi & 8) << 6);
    uint32_t sz = (czi & 1) | ((czi & 2) << 2) | ((czi & 4) << 4) | ((czi & 8) << 6);
    return (int)(sx | (sy << 1) | (sz << 2));
}

// ---------------------------------------------------------------------------
// Rare fallback: exact serial extraction over the scanned groups (masked).
// ---------------------------------------------------------------------------
__device__ __attribute__((noinline)) int serial_topk_masked(
    const vf4* __restrict__ Psort, vf4 q, int lane, ull sm0, ull sm1) {
    ull k0 = SENTKEY, k1 = SENTKEY, k2 = SENTKEY, k3 = SENTKEY;
    int s0 = 0, s1 = 0, s2 = 0, s3 = 0;
    float th = __builtin_inff();
    for (int gid = 0; gid < NGRP; ++gid) {
        bool sel = (gid < 64) ? ((sm0 >> gid) & 1ull) : ((sm1 >> (gid - 64)) & 1ull);
        if (!sel) continue;
        vf4 p = Psort[(gid << 6) + lane];
        float d2 = d2_exact(q, p);
        uint32_t oi = __float_as_uint(p.w);
        ull key = ((ull)__float_as_uint(d2) << 13) | oi;
        if (d2 <= th && key < k3) {
            k3 = key; s3 = gid;
            if (k3 < k2) { ull t = k2; k2 = k3; k3 = t; int ts = s2; s2 = s3; s3 = ts; }
            if (k2 < k1) { ull t = k1; k1 = k2; k2 = t; int ts = s1; s1 = s2; s2 = ts; }
            if (k1 < k0) { ull t = k0; k0 = k1; k1 = t; int ts = s0; s0 = s1; s1 = ts; }
            th = __uint_as_float((uint32_t)(k3 >> 13));
        }
    }
    ull em0 = 0ull, em1 = 0ull;
    int cnt = 4, my_ind = 0;
    for (int r = 0; r < KNN; ++r) {
        ull gmin = wave_min_u64(k0);
        int widx = (int)(gmin & 0x1FFFull);
        if (lane == r) my_ind = widx;
        if (k0 == gmin) {
            int g = s0;
            if (g < 64) em0 |= 1ull << g; else em1 |= 1ull << (g - 64);
            k0 = k1; k1 = k2; k2 = k3; k3 = SENTKEY;
            s0 = s1; s1 = s2; s2 = s3;
            if (--cnt == 0) {
                k0 = k1 = k2 = k3 = SENTKEY;
                float th2 = __builtin_inff();
                for (int gid = 0; gid < NGRP; ++gid) {
                    bool sel = (gid < 64) ? ((sm0 >> gid) & 1ull)
                                          : ((sm1 >> (gid - 64)) & 1ull);
                    bool ex = (gid < 64) ? ((em0 >> gid) & 1ull)
                                         : ((em1 >> (gid - 64)) & 1ull);
                    if (!sel || ex) continue;
                    vf4 p = Psort[(gid << 6) + lane];
                    float d2 = d2_exact(q, p);
                    uint32_t oi = __float_as_uint(p.w);
                    ull key = ((ull)__float_as_uint(d2) << 13) | oi;
                    if (d2 <= th2 && key < k3) {
                        k3 = key; s3 = gid;
                        if (k3 < k2) { ull t = k2; k2 = k3; k3 = t; int ts = s2; s2 = s3; s3 = ts; }
                        if (k2 < k1) { ull t = k1; k1 = k2; k2 = t; int ts = s1; s1 = s2; s2 = ts; }
                        if (k1 < k0) { ull t = k0; k0 = k1; k1 = t; int ts = s0; s0 = s1; s1 = ts; }
                        th2 = __uint_as_float((uint32_t)(k3 >> 13));
                    }
                }
                cnt = 4;
            }
        }
    }
    return my_ind;
}

// ---------------------------------------------------------------------------
// Fused build: per batch block (1024 thr): SoA convert + LDS histogram +
// LDS prefix + scatter to morton order + per-group bbox. One dispatch.
// ---------------------------------------------------------------------------
__global__ __launch_bounds__(1024) void build_kernel(const float* __restrict__ xyz,
                                                     vf4* __restrict__ pc4,
                                                     vf4* __restrict__ sortedP,
                                                     vf4* __restrict__ bC,
                                                     vf4* __restrict__ bH) {
    const int b = (int)blockIdx.x;
    const int tid = (int)threadIdx.x;
    __shared__ int cellc[NCELL];   // histogram -> cursor
    __shared__ int part[1024];

    for (int i = tid; i < NCELL; i += 1024) cellc[i] = 0;
    __syncthreads();

    vf4 v[8];
    int c[8];
#pragma unroll
    for (int j = 0; j < 8; ++j) {
        const int pi = j * 1024 + tid;
        const size_t src = ((size_t)b * NPTS + pi) * 3;
        v[j].x = xyz[src + 0];
        v[j].y = xyz[src + 1];
        v[j].z = xyz[src + 2];
        v[j].w = 0.f;
        pc4[(size_t)b * NPTS + pi] = v[j];
        c[j] = cell_of(v[j].x, v[j].y, v[j].z);
        atomicAdd(&cellc[c[j]], 1);
    }
    __syncthreads();

    // exclusive prefix over 4096 cells (4 per thread + block scan of 1024)
    const int base4 = tid * 4;
    int v0 = cellc[base4], v1 = cellc[base4 + 1], v2 = cellc[base4 + 2], v3 = cellc[base4 + 3];
    int s = v0 + v1 + v2 + v3;
    part[tid] = s;
    __syncthreads();
    for (int off = 1; off < 1024; off <<= 1) {
        int t = (tid >= off) ? part[tid - off] : 0;
        __syncthreads();
        part[tid] += t;
        __syncthreads();
    }
    int excl = part[tid] - s;
    cellc[base4] = excl;
    cellc[base4 + 1] = excl + v0;
    cellc[base4 + 2] = excl + v0 + v1;
    cellc[base4 + 3] = excl + v0 + v1 + v2;
    __syncthreads();

    // scatter into morton-sorted order; .w carries original index bits
#pragma unroll
    for (int j = 0; j < 8; ++j) {
        const int pi = j * 1024 + tid;
        int pos = atomicAdd(&cellc[c[j]], 1);
        vf4 t = v[j];
        t.w = __uint_as_float((uint32_t)pi);
        sortedP[(size_t)b * NPTS + pos] = t;
    }
    __syncthreads();

    // per-group bbox: 16 waves, 8 groups each
    const int wv = tid >> 6, lane = tid & 63;
    for (int g = wv; g < NGRP; g += 16) {
        vf4 p = sortedP[(size_t)b * NPTS + (g << 6) + lane];
        float mnx = p.x, mxx = p.x, mny = p.y, mxy = p.y, mnz = p.z, mxz = p.z;
#pragma unroll
        for (int off = 32; off; off >>= 1) {
            mnx = fminf(mnx, __shfl_xor(mnx, off, 64));
            mxx = fmaxf(mxx, __shfl_xor(mxx, off, 64));
            mny = fminf(mny, __shfl_xor(mny, off, 64));
            mxy = fmaxf(mxy, __shfl_xor(mxy, off, 64));
            mnz = fminf(mnz, __shfl_xor(mnz, off, 64));
            mxz = fmaxf(mxz, __shfl_xor(mxz, off, 64));
        }
        if (lane == 0) {
            vf4 cc, hh;
            cc.x = (mnx + mxx) * 0.5f; cc.y = (mny + mxy) * 0.5f;
            cc.z = (mnz + mxz) * 0.5f; cc.w = 0.f;
            hh.x = (mxx - mnx) * 0.5f; hh.y = (mxy - mny) * 0.5f;
            hh.z = (mxz - mnz) * 0.5f; hh.w = 0.f;
            bC[b * NGRP + g] = cc;
            bH[b * NGRP + g] = hh;
        }
    }
}

// ---------------------------------------------------------------------------
// Main refine: one wave per chain. Ballot group selection + deep prefetch +
// threshold-compact/all-pairs-rank ordered top-32 (no bitonic, no spills).
// ---------------------------------------------------------------------------
__global__ __launch_bounds__(256) void refine_kernel(
    const vf4* __restrict__ pc4, const vf4* __restrict__ sortedP,
    const vf4* __restrict__ bC, const vf4* __restrict__ bH,
    const float* __restrict__ center, const int* __restrict__ idx_in,
    float* __restrict__ pts_ws, int* __restrict__ idx_ws,
    int* __restrict__ grp_ws, int* __restrict__ conv_ws) {
    const int wv = (int)((blockIdx.x * blockDim.x + threadIdx.x) >> 6);
    const int lane = (int)(threadIdx.x & 63);
    const int w = (int)(threadIdx.x >> 6);
    const int b = wv >> 10;
    const vf4* __restrict__ Porig = pc4 + ((size_t)b << 13);
    const vf4* __restrict__ Psort = sortedP + ((size_t)b << 13);

    __shared__ vf4 nbh[4][KNN];
    __shared__ ull ckeys[4][132];          // compacted candidates (+4 sentinel pad)
    __shared__ uint32_t cord[4][KNN];      // ordered top-32 index bits
    __shared__ ull tau_s[4];               // rank-31 key

    // bboxes are loop-invariant: lane owns groups (lane) and (64+lane)
    const int b128 = b << 7;
    const vf4 c0 = bC[b128 + lane], h0 = bH[b128 + lane];
    const vf4 c1 = bC[b128 + 64 + lane], h1 = bH[b128 + 64 + lane];

    const size_t ch = (size_t)wv;
    vf4 q;
    q.x = center[ch * 3 + 0];
    q.y = center[ch * 3 + 1];
    q.z = center[ch * 3 + 2];
    q.w = 0.f;
    int qidx = idx_in[ch];

    int conv = MAXIT;
    int my_ind = 0;

    for (int it = 0;; ++it) {
        // ---- per-lane bbox min-d2 for its 2 groups ----
        const float m0 = bbox_mind2(q, c0, h0);
        const float m1 = bbox_mind2(q, c1, h1);
        // 32-bit quantized keys: (mind2 truncated to 25 bits) | gid. Monotone
        // truncation; a near-tie mis-pick only loosens B, never unsound.
        const uint32_t q0k = (__float_as_uint(m0) & 0xFFFFFF80u) | (uint32_t)lane;
        const uint32_t q1k = (__float_as_uint(m1) & 0xFFFFFF80u) | (uint32_t)(64 + lane);

        // ---- two smallest via one 6-step 32-bit butterfly ----
        uint32_t s1 = q0k < q1k ? q0k : q1k, s2 = q0k < q1k ? q1k : q0k;
#pragma unroll
        for (int off = 32; off; off >>= 1) {
            uint32_t o1 = (uint32_t)__shfl_xor((int)s1, off, 64);
            uint32_t o2 = (uint32_t)__shfl_xor((int)s2, off, 64);
            uint32_t hi = s1 > o1 ? s1 : o1;
            uint32_t lo2 = s2 < o2 ? s2 : o2;
            s1 = s1 < o1 ? s1 : o1;
            s2 = hi < lo2 ? hi : lo2;
        }
        const int g1 = (int)(s1 & 127u);
        const int g2 = (int)(s2 & 127u);

        // ---- scan the 2 nearest groups (loads issued together) ----
        ull k0 = SENTKEY, k1 = SENTKEY, k2 = SENTKEY, k3 = SENTKEY;
        float th = __builtin_inff();
        {
            const vf4 p1 = Psort[(g1 << 6) + lane];
            const vf4 p2 = Psort[(g2 << 6) + lane];
            float d2a = d2_exact(q, p1);
            insert_top4(((ull)__float_as_uint(d2a) << 13) | __float_as_uint(p1.w),
                        k0, k1, k2, k3, th);
            float d2b = d2_exact(q, p2);
            if (d2b <= th)
                insert_top4(((ull)__float_as_uint(d2b) << 13) | __float_as_uint(p2.w),
                            k0, k1, k2, k3, th);
        }

        // ---- sound bound B: max of 32 distinct actual candidate d2's ----
        // (32 pairwise-mins are 32 distinct candidates; max >= 32nd of union)
        uint32_t tb;
        {
            ull t = k0;
            ull o = (ull)__shfl_xor((unsigned long long)t, 32, 64);
            t = o < t ? o : t;
            tb = (uint32_t)(t >> 13);   // d2 bits (nonneg float: bit order = fp order)
#pragma unroll
            for (int off = 32; off; off >>= 1) {
                uint32_t ob = (uint32_t)__shfl_xor((int)tb, off, 64);
                tb = ob > tb ? ob : tb;
            }
        }
        const float Bd = __uint_as_float(tb);

        // ---- one ballot selects every group that can hold a top-32 point ----
        ull sm0 = __ballot(m0 <= Bd);
        ull sm1 = __ballot(m1 <= Bd);
        ull fb0 = sm0, fb1 = sm1;   // scanned-set for fallback
        if (g1 < 64) fb0 |= 1ull << g1; else fb1 |= 1ull << (g1 - 64);
        if (g2 < 64) fb0 |= 1ull << g2; else fb1 |= 1ull << (g2 - 64);
        if (g1 < 64) sm0 &= ~(1ull << g1); else sm1 &= ~(1ull << (g1 - 64));
        if (g2 < 64) sm0 &= ~(1ull << g2); else sm1 &= ~(1ull << (g2 - 64));

        // ---- deep-prefetch masked scan: batches of 8 loads in flight ----
        {
            ull mm0 = sm0, mm1 = sm1;
            while (mm0 | mm1) {
                int gl[8];
                vf4 pf[8];
#pragma unroll
                for (int j = 0; j < 8; ++j) {
                    int gg = -1;
                    if (mm0)      { gg = (int)__builtin_ctzll(mm0); mm0 &= mm0 - 1; }
                    else if (mm1) { gg = 64 + (int)__builtin_ctzll(mm1); mm1 &= mm1 - 1; }
                    gl[j] = gg;
                    if (gg >= 0) pf[j] = Psort[(gg << 6) + lane];
                }
#pragma unroll
                for (int j = 0; j < 8; ++j) {
                    if (gl[j] >= 0) {
                        const float d2 = d2_exact(q, pf[j]);
                        if (d2 <= th)
                            insert_top4(((ull)__float_as_uint(d2) << 13) |
                                            __float_as_uint(pf[j].w),
                                        k0, k1, k2, k3, th);
                    }
                }
            }
        }
        const ull prek3 = k3;

        // ---- threshold-compact + all-pairs rank ordered top-32 ----
        // candidates = queue entries with d2bits <= tb; all top-32 qualify
        // (their keys <= B => d2 <= Bd) and m >= 32 (the 32 pairwise-mins).
        uint32_t cc = ((uint32_t)(k0 >> 13) <= tb ? 1u : 0u) +
                      ((uint32_t)(k1 >> 13) <= tb ? 1u : 0u) +
                      ((uint32_t)(k2 >> 13) <= tb ? 1u : 0u) +
                      ((uint32_t)(k3 >> 13) <= tb ? 1u : 0u);
        const ull cb0 = __ballot(cc & 1u);
        const ull cb1 = __ballot(cc & 2u);
        const ull cb2 = __ballot(cc & 4u);
        const int m = __popcll(cb0) + 2 * __popcll(cb1) + 4 * __popcll(cb2);
        bool need_serial = (m > 128);
        if (!need_serial) {
            const ull lm = (1ull << lane) - 1ull;
            const int off = __popcll(cb0 & lm) + 2 * __popcll(cb1 & lm) +
                            4 * __popcll(cb2 & lm);
            // sentinel pad so the rank loop can run in steps of 4
            if (lane < 4) ckeys[w][m + lane] = ~0ull;
            if (cc > 0) ckeys[w][off + 0] = k0;   // queue sorted: first cc qualify
            if (cc > 1) ckeys[w][off + 1] = k1;
            if (cc > 2) ckeys[w][off + 2] = k2;
            if (cc > 3) ckeys[w][off + 3] = k3;
            __asm__ volatile("s_waitcnt lgkmcnt(0)" ::: "memory");
            const ull mk0 = (lane < m) ? ckeys[w][lane] : ~0ull;
            const ull mk1 = (lane + 64 < m) ? ckeys[w][lane + 64] : ~0ull;
            int r0 = 0, r1 = 0;
            const int mp = (m + 3) & ~3;
            for (int i = 0; i < mp; i += 4) {
                const ull ka = ckeys[w][i + 0];
                const ull kb = ckeys[w][i + 1];
                const ull kc = ckeys[w][i + 2];
                const ull kd = ckeys[w][i + 3];
                r0 += (int)(ka < mk0) + (int)(kb < mk0) + (int)(kc < mk0) + (int)(kd < mk0);
                r1 += (int)(ka < mk1) + (int)(kb < mk1) + (int)(kc < mk1) + (int)(kd < mk1);
            }
            if (lane < m && r0 < KNN) {
                cord[w][r0] = (uint32_t)(mk0 & 0x1FFFull);
                if (r0 == KNN - 1) tau_s[w] = mk0;
            }
            if (lane + 64 < m && r1 < KNN) {
                cord[w][r1] = (uint32_t)(mk1 & 0x1FFFull);
                if (r1 == KNN - 1) tau_s[w] = mk1;
            }
            __asm__ volatile("s_waitcnt lgkmcnt(0)" ::: "memory");
            const ull tau = tau_s[w];
            const ull bad = __ballot(prek3 < tau);   // lane may have truncated a winner
            if (bad != 0ull) need_serial = true;
            else my_ind = (lane < KNN) ? (int)cord[w][lane] : 0;
        }
        if (need_serial) my_ind = serial_topk_masked(Psort, q, lane, fb0, fb1);

        if (it == MAXIT) break;  // final step's ind recorded; conv stays MAXIT

        // ---- centroid: stage 32 ordered neighbors to LDS, sequential fold ----
        vf4 myp = q;
        if (lane < KNN) {
            myp = Porig[my_ind];
            nbh[w][lane] = myp;
        }
        __asm__ volatile("s_waitcnt lgkmcnt(0)" ::: "memory");
        float sx = 0.f, sy = 0.f, sz = 0.f;
#pragma unroll
        for (int j = 0; j < KNN; ++j) {
            vf4 pj = nbh[w][j];
            sx = __fadd_rn(sx, pj.x);
            sy = __fadd_rn(sy, pj.y);
            sz = __fadd_rn(sz, pj.z);
        }
        const float gx = __fmul_rn(sx, 0.03125f);
        const float gy = __fmul_rn(sy, 0.03125f);
        const float gz = __fmul_rn(sz, 0.03125f);

        // ---- per-neighbor distance to centroid (post-sqrt ordering) ----
        float dj = __builtin_inff();
        if (lane < KNN) {
            const float dx = __fsub_rn(myp.x, gx);
            const float dy = __fsub_rn(myp.y, gy);
            const float dz = __fsub_rn(myp.z, gz);
            dj = sqrtf(__fadd_rn(__fadd_rn(__fmul_rn(dx, dx), __fmul_rn(dy, dy)),
                                 __fmul_rn(dz, dz)));
        }
        const uint32_t db = __float_as_uint(dj);  // nonneg: bit order == fp order
        const uint32_t d0 = (uint32_t)__shfl((int)db, 0, 64);
        const ull bal = __ballot(db < d0);
        if (__popcll(bal) <= TOPC - 1) { conv = it; break; }

        // move target: lexicographic argmin of (dist, j)
        uint32_t m2 = db;
#pragma unroll
        for (int off = 32; off; off >>= 1) {
            uint32_t o = (uint32_t)__shfl_xor((int)m2, off, 64);
            m2 = o < m2 ? o : m2;
        }
        const ull balm = __ballot(db == m2);
        const int jm = __ffsll((unsigned long long)balm) - 1;
        const int nidx = __shfl(my_ind, jm, 64);
        qidx = nidx;
        q = Porig[nidx];
        q.w = 0.f;
    }

    if (lane < KNN) grp_ws[ch * KNN + lane] = my_ind;
    if (lane == 0) {
        pts_ws[ch * 3 + 0] = q.x;
        pts_ws[ch * 3 + 1] = q.y;
        pts_ws[ch * 3 + 2] = q.z;
        idx_ws[ch] = qidx;
        conv_ws[ch] = conv;
    }
}

// ---------------------------------------------------------------------------
// Order: stable rank by (conv, s) via 17-bin counting
// ---------------------------------------------------------------------------
__global__ __launch_bounds__(1024) void order_kernel(
    const float* __restrict__ pts_ws, const int* __restrict__ idx_ws,
    const int* __restrict__ grp_ws, const int* __restrict__ conv_ws,
    float* __restrict__ out) {
    const int b = (int)blockIdx.x;
    const int s = (int)threadIdx.x;
    const int w = s >> 6, l = s & 63;
    __shared__ int wavecnt[16][MAXIT + 1];
    __shared__ int binbase[MAXIT + 1];
    const size_t ch = (size_t)b * SCH + s;
    const int c = conv_ws[ch];
    int rw = 0;
#pragma unroll
    for (int v = 0; v <= MAXIT; ++v) {
        ull bal = __ballot(c == v);
        if (l == 0) wavecnt[w][v] = (int)__popcll(bal);
        if (c == v) rw = (int)__popcll(bal & ((1ull << l) - 1ull));
    }
    __syncthreads();
    if (s == 0) {
        int acc = 0;
        for (int v = 0; v <= MAXIT; ++v) {
            int t = 0;
            for (int w2 = 0; w2 < 16; ++w2) t += wavecnt[w2][v];
            binbase[v] = acc;
            acc += t;
        }
    }
    __syncthreads();
    int pos = binbase[c] + rw;
    for (int w2 = 0; w2 < w; ++w2) pos += wavecnt[w2][c];

    float* __restrict__ C  = out;                              // (B,S,3)
    float* __restrict__ I1 = out + (size_t)BATCH * SCH * 3;    // (B,S)
    float* __restrict__ I2 = I1 + (size_t)BATCH * SCH;         // (B,S,K)
    const size_t o = (size_t)b * SCH + pos;
    C[o * 3 + 0] = pts_ws[ch * 3 + 0];
    C[o * 3 + 1] = pts_ws[ch * 3 + 1];
    C[o * 3 + 2] = pts_ws[ch * 3 + 2];
    I1[o] = (float)idx_ws[ch];
#pragma unroll
    for (int k = 0; k < KNN; ++k) I2[o * KNN + k] = (float)grp_ws[ch * KNN + k];
}

extern "C" void kernel_launch(void* const* d_in, const int* in_sizes, int n_in,
                              void* d_out, int out_size, void* d_ws, size_t ws_size,
                              hipStream_t stream) {
    const float* xyz    = (const float*)d_in[0];  // (8,8192,3) f32
    const float* center = (const float*)d_in[1];  // (8,1024,3) f32
    const int*   idx_in = (const int*)d_in[2];    // (8,1024)   i32
    float* out = (float*)d_out;

    // workspace layout (~3.3 MB)
    char* wp = (char*)d_ws;
    vf4* pc4     = (vf4*)wp;  wp += (size_t)BATCH * NPTS * sizeof(vf4);   // 1 MB
    vf4* sortedP = (vf4*)wp;  wp += (size_t)BATCH * NPTS * sizeof(vf4);   // 1 MB
    vf4* bC      = (vf4*)wp;  wp += (size_t)BATCH * NGRP * sizeof(vf4);   // 16 KB
    vf4* bH      = (vf4*)wp;  wp += (size_t)BATCH * NGRP * sizeof(vf4);   // 16 KB
    float* pts_ws = (float*)wp; wp += (size_t)BATCH * SCH * 3 * 4;
    int*   idx_ws = (int*)wp;   wp += (size_t)BATCH * SCH * 4;
    int*   grp_ws = (int*)wp;   wp += (size_t)BATCH * SCH * KNN * 4;      // 1 MB
    int*   conv_ws = (int*)wp;

    build_kernel<<<BATCH, 1024, 0, stream>>>(xyz, pc4, sortedP, bC, bH);

    const int chains = BATCH * SCH;                 // 8192 waves, 1 per chain
    refine_kernel<<<chains * 64 / 256, 256, 0, stream>>>(
        pc4, sortedP, bC, bH, center, idx_in, pts_ws, idx_ws, grp_ws, conv_ws);
    order_kernel<<<BATCH, SCH, 0, stream>>>(pts_ws, idx_ws, grp_ws, conv_ws, out);
}

// Round 8
// 254.402 us; speedup vs baseline: 1.5468x; 1.5468x over previous
//
#include <hip/hip_runtime.h>
#include <stdint.h>

#define BATCH   8
#define NPTS    8192
#define SCH     1024
#define KNN     32
#define TOPC    5
#define MAXIT   16
#define NCELL   4096     // 16^3 morton cells
#define NGRP    128      // groups of 64 per batch

typedef unsigned long long ull;
typedef float vf2 __attribute__((ext_vector_type(2)));
typedef float vf4 __attribute__((ext_vector_type(4)));

// sentinel: unpacks to +inf d2, never enters top-32
#define SENTKEY ((((ull)0x7F800000u) << 13) | 0x1FFFull)

// ---------------------------------------------------------------------------
// Exact d2: separate mul/add roundings (no FMA), order ((dx2+dy2)+dz2) = numpy.
// ---------------------------------------------------------------------------
__device__ __forceinline__ float d2_exact(vf4 q, vf4 p) {
#pragma clang fp contract(off)
    vf2 d = q.xy - p.xy;
    vf2 s = d * d;
    float dz = q.z - p.z;
    float sz = dz * dz;
    return (s.x + s.y) + sz;
}

__device__ __forceinline__ void insert_top4(ull key, ull& k0, ull& k1, ull& k2,
                                            ull& k3, float& th) {
    if (key < k3) {
        k3 = key;
        { bool c = k3 < k2; ull mn = c ? k3 : k2, mx = c ? k2 : k3; k2 = mn; k3 = mx; }
        { bool c = k2 < k1; ull mn = c ? k2 : k1, mx = c ? k1 : k2; k1 = mn; k2 = mx; }
        { bool c = k1 < k0; ull mn = c ? k1 : k0, mx = c ? k0 : k1; k0 = mn; k1 = mx; }
        th = __uint_as_float((uint32_t)(k3 >> 13));
    }
}

__device__ __forceinline__ ull wave_min_u64(ull k) {
#pragma unroll
    for (int off = 32; off; off >>= 1) {
        ull o = (ull)__shfl_xor((unsigned long long)k, off, 64);
        k = o < k ? o : k;
    }
    return k;
}

// conservative (under-estimated) squared min distance from q to group bbox
__device__ __forceinline__ float bbox_mind2(vf4 q, vf4 c, vf4 h) {
    float dx = fmaxf(fabsf(q.x - c.x) - h.x, 0.f);
    float dy = fmaxf(fabsf(q.y - c.y) - h.y, 0.f);
    float dz = fmaxf(fabsf(q.z - c.z) - h.z, 0.f);
    return (dx * dx + dy * dy + dz * dz) * 0.9999f;
}

// bitonic helpers
__device__ __forceinline__ ull cx(ull v, int xl, bool keepmin) {
    ull o = (ull)__shfl_xor((unsigned long long)v, xl, 64);
    return ((v < o) == keepmin) ? v : o;
}
__device__ __forceinline__ void cswap(ull& a, ull& b, bool up) {
    bool lt = a < b;
    ull mn = lt ? a : b, mx = lt ? b : a;
    a = up ? mn : mx;
    b = up ? mx : mn;
}

// morton cell id from point (16^3 over [-4,4], clamped)
__device__ __forceinline__ int cell_of(float x, float y, float z) {
    int cxi = min(15, max(0, (int)floorf((x + 4.0f) * 2.0f)));
    int cyi = min(15, max(0, (int)floorf((y + 4.0f) * 2.0f)));
    int czi = min(15, max(0, (int)floorf((z + 4.0f) * 2.0f)));
    uint32_t sx = (cxi & 1) | ((cxi & 2) << 2) | ((cxi & 4) << 4) | ((cxi & 8) << 6);
    uint32_t sy = (cyi & 1) | ((cyi & 2) << 2) | ((cyi & 4) << 4) | ((cyi & 8) << 6);
    uint32_t sz = (czi & 1) | ((czi & 2) << 2) | ((czi & 4) << 4) | ((czi & 8) << 6);
    return (int)(sx | (sy << 1) | (sz << 2));
}

// ---------------------------------------------------------------------------
// Rare fallback: exact serial extraction over the scanned groups (masked).
// ---------------------------------------------------------------------------
__device__ __attribute__((noinline)) int serial_topk_masked(
    const vf4* __restrict__ Psort, vf4 q, int lane, ull sm0, ull sm1) {
    ull k0 = SENTKEY, k1 = SENTKEY, k2 = SENTKEY, k3 = SENTKEY;
    int s0 = 0, s1 = 0, s2 = 0, s3 = 0;
    float th = __builtin_inff();
    for (int gid = 0; gid < NGRP; ++gid) {
        bool sel = (gid < 64) ? ((sm0 >> gid) & 1ull) : ((sm1 >> (gid - 64)) & 1ull);
        if (!sel) continue;
        vf4 p = Psort[(gid << 6) + lane];
        float d2 = d2_exact(q, p);
        uint32_t oi = __float_as_uint(p.w);
        ull key = ((ull)__float_as_uint(d2) << 13) | oi;
        if (d2 <= th && key < k3) {
            k3 = key; s3 = gid;
            if (k3 < k2) { ull t = k2; k2 = k3; k3 = t; int ts = s2; s2 = s3; s3 = ts; }
            if (k2 < k1) { ull t = k1; k1 = k2; k2 = t; int ts = s1; s1 = s2; s2 = ts; }
            if (k1 < k0) { ull t = k0; k0 = k1; k1 = t; int ts = s0; s0 = s1; s1 = ts; }
            th = __uint_as_float((uint32_t)(k3 >> 13));
        }
    }
    ull em0 = 0ull, em1 = 0ull;
    int cnt = 4, my_ind = 0;
    for (int r = 0; r < KNN; ++r) {
        ull gmin = wave_min_u64(k0);
        int widx = (int)(gmin & 0x1FFFull);
        if (lane == r) my_ind = widx;
        if (k0 == gmin) {
            int g = s0;
            if (g < 64) em0 |= 1ull << g; else em1 |= 1ull << (g - 64);
            k0 = k1; k1 = k2; k2 = k3; k3 = SENTKEY;
            s0 = s1; s1 = s2; s2 = s3;
            if (--cnt == 0) {
                k0 = k1 = k2 = k3 = SENTKEY;
                float th2 = __builtin_inff();
                for (int gid = 0; gid < NGRP; ++gid) {
                    bool sel = (gid < 64) ? ((sm0 >> gid) & 1ull)
                                          : ((sm1 >> (gid - 64)) & 1ull);
                    bool ex = (gid < 64) ? ((em0 >> gid) & 1ull)
                                         : ((em1 >> (gid - 64)) & 1ull);
                    if (!sel || ex) continue;
                    vf4 p = Psort[(gid << 6) + lane];
                    float d2 = d2_exact(q, p);
                    uint32_t oi = __float_as_uint(p.w);
                    ull key = ((ull)__float_as_uint(d2) << 13) | oi;
                    if (d2 <= th2 && key < k3) {
                        k3 = key; s3 = gid;
                        if (k3 < k2) { ull t = k2; k2 = k3; k3 = t; int ts = s2; s2 = s3; s3 = ts; }
                        if (k2 < k1) { ull t = k1; k1 = k2; k2 = t; int ts = s1; s1 = s2; s2 = ts; }
                        if (k1 < k0) { ull t = k0; k0 = k1; k1 = t; int ts = s0; s0 = s1; s1 = ts; }
                        th2 = __uint_as_float((uint32_t)(k3 >> 13));
                    }
                }
                cnt = 4;
            }
        }
    }
    return my_ind;
}

// ---------------------------------------------------------------------------
// Split parallel build (r4-style, measured ~35 us cheaper than 8-block fused)
// ---------------------------------------------------------------------------
__global__ __launch_bounds__(256) void prep_kernel(const float* __restrict__ xyz,
                                                   vf4* __restrict__ pc4,
                                                   int* __restrict__ counts) {
    int i = (int)(blockIdx.x * blockDim.x + threadIdx.x);
    if (i >= BATCH * NPTS) return;
    vf4 v;
    v.x = xyz[(size_t)i * 3 + 0];
    v.y = xyz[(size_t)i * 3 + 1];
    v.z = xyz[(size_t)i * 3 + 2];
    v.w = 0.f;
    pc4[i] = v;
    int b = i >> 13;
    atomicAdd(&counts[b * NCELL + cell_of(v.x, v.y, v.z)], 1);
}

__global__ __launch_bounds__(1024) void scan_kernel(const int* __restrict__ counts,
                                                    int* __restrict__ cursor) {
    int b = (int)blockIdx.x, tid = (int)threadIdx.x;
    __shared__ int part[1024];
    int base = b * NCELL + tid * 4;
    int v0 = counts[base], v1 = counts[base + 1], v2 = counts[base + 2], v3 = counts[base + 3];
    int s = v0 + v1 + v2 + v3;
    part[tid] = s;
    __syncthreads();
    for (int off = 1; off < 1024; off <<= 1) {
        int t = (tid >= off) ? part[tid - off] : 0;
        __syncthreads();
        part[tid] += t;
        __syncthreads();
    }
    int excl = part[tid] - s;
    cursor[base] = excl;
    cursor[base + 1] = excl + v0;
    cursor[base + 2] = excl + v0 + v1;
    cursor[base + 3] = excl + v0 + v1 + v2;
}

__global__ __launch_bounds__(256) void scatter_kernel(const vf4* __restrict__ pc4,
                                                      int* __restrict__ cursor,
                                                      vf4* __restrict__ sortedP) {
    int i = (int)(blockIdx.x * blockDim.x + threadIdx.x);
    if (i >= BATCH * NPTS) return;
    vf4 v = pc4[i];
    int b = i >> 13, pi = i & (NPTS - 1);
    int c = cell_of(v.x, v.y, v.z);
    int pos = atomicAdd(&cursor[b * NCELL + c], 1);
    v.w = __uint_as_float((uint32_t)pi);
    sortedP[((size_t)b << 13) + pos] = v;
}

__global__ __launch_bounds__(256) void bbox_kernel(const vf4* __restrict__ sortedP,
                                                   vf4* __restrict__ bC,
                                                   vf4* __restrict__ bH) {
    int g = (int)((blockIdx.x * blockDim.x + threadIdx.x) >> 6);  // 0..B*NGRP-1
    int lane = (int)(threadIdx.x & 63);
    vf4 p = sortedP[((size_t)g << 6) + lane];
    float mnx = p.x, mxx = p.x, mny = p.y, mxy = p.y, mnz = p.z, mxz = p.z;
#pragma unroll
    for (int off = 32; off; off >>= 1) {
        mnx = fminf(mnx, __shfl_xor(mnx, off, 64));
        mxx = fmaxf(mxx, __shfl_xor(mxx, off, 64));
        mny = fminf(mny, __shfl_xor(mny, off, 64));
        mxy = fmaxf(mxy, __shfl_xor(mxy, off, 64));
        mnz = fminf(mnz, __shfl_xor(mnz, off, 64));
        mxz = fmaxf(mxz, __shfl_xor(mxz, off, 64));
    }
    if (lane == 0) {
        vf4 cc, hh;
        cc.x = (mnx + mxx) * 0.5f; cc.y = (mny + mxy) * 0.5f;
        cc.z = (mnz + mxz) * 0.5f; cc.w = 0.f;
        hh.x = (mxx - mnx) * 0.5f; hh.y = (mxy - mny) * 0.5f;
        hh.z = (mxz - mnz) * 0.5f; hh.w = 0.f;
        bC[g] = cc;
        bH[g] = hh;
    }
}

// ---------------------------------------------------------------------------
// Main refine: one wave per chain. Ballot group selection + 8-deep prefetch
// (in registers — NO min-waves clause, spills are worse than occupancy here)
// + in-register wave bitonic for the ordered top-32.
// ---------------------------------------------------------------------------
__global__ __launch_bounds__(256) void refine_kernel(
    const vf4* __restrict__ pc4, const vf4* __restrict__ sortedP,
    const vf4* __restrict__ bC, const vf4* __restrict__ bH,
    const float* __restrict__ center, const int* __restrict__ idx_in,
    float* __restrict__ pts_ws, int* __restrict__ idx_ws,
    int* __restrict__ grp_ws, int* __restrict__ conv_ws) {
    const int wv = (int)((blockIdx.x * blockDim.x + threadIdx.x) >> 6);
    const int lane = (int)(threadIdx.x & 63);
    const int w = (int)(threadIdx.x >> 6);
    const int b = wv >> 10;
    const vf4* __restrict__ Porig = pc4 + ((size_t)b << 13);
    const vf4* __restrict__ Psort = sortedP + ((size_t)b << 13);

    __shared__ vf4 nbh[4][KNN];

    // bboxes are loop-invariant: lane owns groups (lane) and (64+lane)
    const int b128 = b << 7;
    const vf4 c0 = bC[b128 + lane], h0 = bH[b128 + lane];
    const vf4 c1 = bC[b128 + 64 + lane], h1 = bH[b128 + 64 + lane];

    const size_t ch = (size_t)wv;
    vf4 q;
    q.x = center[ch * 3 + 0];
    q.y = center[ch * 3 + 1];
    q.z = center[ch * 3 + 2];
    q.w = 0.f;
    int qidx = idx_in[ch];

    int conv = MAXIT;
    int my_ind = 0;

    for (int it = 0;; ++it) {
        // ---- per-lane bbox min-d2 for its 2 groups ----
        const float m0 = bbox_mind2(q, c0, h0);
        const float m1 = bbox_mind2(q, c1, h1);
        // 32-bit quantized keys: (mind2 truncated to 25 bits) | gid. Monotone
        // truncation; a near-tie mis-pick only loosens B, never unsound.
        const uint32_t q0k = (__float_as_uint(m0) & 0xFFFFFF80u) | (uint32_t)lane;
        const uint32_t q1k = (__float_as_uint(m1) & 0xFFFFFF80u) | (uint32_t)(64 + lane);

        // ---- two smallest via one 6-step 32-bit butterfly ----
        uint32_t s1 = q0k < q1k ? q0k : q1k, s2 = q0k < q1k ? q1k : q0k;
#pragma unroll
        for (int off = 32; off; off >>= 1) {
            uint32_t o1 = (uint32_t)__shfl_xor((int)s1, off, 64);
            uint32_t o2 = (uint32_t)__shfl_xor((int)s2, off, 64);
            uint32_t hi = s1 > o1 ? s1 : o1;
            uint32_t lo2 = s2 < o2 ? s2 : o2;
            s1 = s1 < o1 ? s1 : o1;
            s2 = hi < lo2 ? hi : lo2;
        }
        const int g1 = (int)(s1 & 127u);
        const int g2 = (int)(s2 & 127u);

        // ---- scan the 2 nearest groups (loads issued together) ----
        ull k0 = SENTKEY, k1 = SENTKEY, k2 = SENTKEY, k3 = SENTKEY;
        float th = __builtin_inff();
        {
            const vf4 p1 = Psort[(g1 << 6) + lane];
            const vf4 p2 = Psort[(g2 << 6) + lane];
            float d2a = d2_exact(q, p1);
            insert_top4(((ull)__float_as_uint(d2a) << 13) | __float_as_uint(p1.w),
                        k0, k1, k2, k3, th);
            float d2b = d2_exact(q, p2);
            if (d2b <= th)
                insert_top4(((ull)__float_as_uint(d2b) << 13) | __float_as_uint(p2.w),
                            k0, k1, k2, k3, th);
        }

        // ---- sound bound B: max of 32 distinct actual candidate d2's ----
        // (32 pairwise-mins are 32 distinct candidates; max >= 32nd of union)
        uint32_t tb;
        {
            ull t = k0;
            ull o = (ull)__shfl_xor((unsigned long long)t, 32, 64);
            t = o < t ? o : t;
            tb = (uint32_t)(t >> 13);   // d2 bits (nonneg float: bit order = fp order)
#pragma unroll
            for (int off = 32; off; off >>= 1) {
                uint32_t ob = (uint32_t)__shfl_xor((int)tb, off, 64);
                tb = ob > tb ? ob : tb;
            }
        }
        const float Bd = __uint_as_float(tb);

        // ---- one ballot selects every group that can hold a top-32 point ----
        ull sm0 = __ballot(m0 <= Bd);
        ull sm1 = __ballot(m1 <= Bd);
        ull fb0 = sm0, fb1 = sm1;   // scanned-set for fallback
        if (g1 < 64) fb0 |= 1ull << g1; else fb1 |= 1ull << (g1 - 64);
        if (g2 < 64) fb0 |= 1ull << g2; else fb1 |= 1ull << (g2 - 64);
        if (g1 < 64) sm0 &= ~(1ull << g1); else sm1 &= ~(1ull << (g1 - 64));
        if (g2 < 64) sm0 &= ~(1ull << g2); else sm1 &= ~(1ull << (g2 - 64));

        // ---- deep-prefetch masked scan: batches of 8 loads in flight ----
        {
            ull mm0 = sm0, mm1 = sm1;
            while (mm0 | mm1) {
                int gl[8];
                vf4 pf[8];
#pragma unroll
                for (int j = 0; j < 8; ++j) {
                    int gg = -1;
                    if (mm0)      { gg = (int)__builtin_ctzll(mm0); mm0 &= mm0 - 1; }
                    else if (mm1) { gg = 64 + (int)__builtin_ctzll(mm1); mm1 &= mm1 - 1; }
                    gl[j] = gg;
                    if (gg >= 0) pf[j] = Psort[(gg << 6) + lane];
                }
#pragma unroll
                for (int j = 0; j < 8; ++j) {
                    if (gl[j] >= 0) {
                        const float d2 = d2_exact(q, pf[j]);
                        if (d2 <= th)
                            insert_top4(((ull)__float_as_uint(d2) << 13) |
                                            __float_as_uint(pf[j].w),
                                        k0, k1, k2, k3, th);
                    }
                }
            }
        }
        const ull prek3 = k3;

        // ---- wave bitonic sort of 256 candidates (sentinel-padded) ----
        const bool odd = (lane & 1) != 0;
        ull a0 = odd ? k3 : k0;
        ull a1 = odd ? k2 : k1;
        ull a2 = odd ? k1 : k2;
        ull a3 = odd ? k0 : k3;
#pragma unroll
        for (int kk = 8; kk <= 256; kk <<= 1) {
            const bool up = (lane & (kk >> 2)) == 0;
#pragma unroll
            for (int d = kk >> 1; d >= 4; d >>= 1) {
                const int xl = d >> 2;
                const bool keepmin = (up == ((lane & xl) == 0));
                a0 = cx(a0, xl, keepmin);
                a1 = cx(a1, xl, keepmin);
                a2 = cx(a2, xl, keepmin);
                a3 = cx(a3, xl, keepmin);
            }
            cswap(a0, a2, up); cswap(a1, a3, up);
            cswap(a0, a1, up); cswap(a2, a3, up);
        }
        // rank r lives at lane r>>2, reg r&3; tau = rank-31 key
        const ull tau = (ull)__shfl((unsigned long long)a3, 7, 64);
        const ull bad = __ballot(prek3 < tau);
        if (bad != 0ull) {
            my_ind = serial_topk_masked(Psort, q, lane, fb0, fb1);
        } else {
            const int src = lane >> 2;
            const uint32_t lo0 = (uint32_t)__shfl((int)(uint32_t)a0, src, 64);
            const uint32_t lo1 = (uint32_t)__shfl((int)(uint32_t)a1, src, 64);
            const uint32_t lo2 = (uint32_t)__shfl((int)(uint32_t)a2, src, 64);
            const uint32_t lo3 = (uint32_t)__shfl((int)(uint32_t)a3, src, 64);
            const int sel = lane & 3;
            uint32_t lo = (sel == 0) ? lo0 : (sel == 1) ? lo1 : (sel == 2) ? lo2 : lo3;
            my_ind = (int)(lo & 0x1FFFu);
        }

        if (it == MAXIT) break;  // final step's ind recorded; conv stays MAXIT

        // ---- centroid: stage 32 ordered neighbors to LDS, sequential fold ----
        vf4 myp = q;
        if (lane < KNN) {
            myp = Porig[my_ind];
            nbh[w][lane] = myp;
        }
        __asm__ volatile("s_waitcnt lgkmcnt(0)" ::: "memory");
        float sx = 0.f, sy = 0.f, sz = 0.f;
#pragma unroll
        for (int j = 0; j < KNN; ++j) {
            vf4 pj = nbh[w][j];
            sx = __fadd_rn(sx, pj.x);
            sy = __fadd_rn(sy, pj.y);
            sz = __fadd_rn(sz, pj.z);
        }
        const float gx = __fmul_rn(sx, 0.03125f);
        const float gy = __fmul_rn(sy, 0.03125f);
        const float gz = __fmul_rn(sz, 0.03125f);

        // ---- per-neighbor distance to centroid (post-sqrt ordering) ----
        float dj = __builtin_inff();
        if (lane < KNN) {
            const float dx = __fsub_rn(myp.x, gx);
            const float dy = __fsub_rn(myp.y, gy);
            const float dz = __fsub_rn(myp.z, gz);
            dj = sqrtf(__fadd_rn(__fadd_rn(__fmul_rn(dx, dx), __fmul_rn(dy, dy)),
                                 __fmul_rn(dz, dz)));
        }
        const uint32_t db = __float_as_uint(dj);  // nonneg: bit order == fp order
        const uint32_t d0 = (uint32_t)__shfl((int)db, 0, 64);
        const ull bal = __ballot(db < d0);
        if (__popcll(bal) <= TOPC - 1) { conv = it; break; }

        // move target: lexicographic argmin of (dist, j)
        uint32_t m2 = db;
#pragma unroll
        for (int off = 32; off; off >>= 1) {
            uint32_t o = (uint32_t)__shfl_xor((int)m2, off, 64);
            m2 = o < m2 ? o : m2;
        }
        const ull balm = __ballot(db == m2);
        const int jm = __ffsll((unsigned long long)balm) - 1;
        const int nidx = __shfl(my_ind, jm, 64);
        qidx = nidx;
        q = Porig[nidx];
        q.w = 0.f;
    }

    if (lane < KNN) grp_ws[ch * KNN + lane] = my_ind;
    if (lane == 0) {
        pts_ws[ch * 3 + 0] = q.x;
        pts_ws[ch * 3 + 1] = q.y;
        pts_ws[ch * 3 + 2] = q.z;
        idx_ws[ch] = qidx;
        conv_ws[ch] = conv;
    }
}

// ---------------------------------------------------------------------------
// Order: stable rank by (conv, s) via 17-bin counting
// ---------------------------------------------------------------------------
__global__ __launch_bounds__(1024) void order_kernel(
    const float* __restrict__ pts_ws, const int* __restrict__ idx_ws,
    const int* __restrict__ grp_ws, const int* __restrict__ conv_ws,
    float* __restrict__ out) {
    const int b = (int)blockIdx.x;
    const int s = (int)threadIdx.x;
    const int w = s >> 6, l = s & 63;
    __shared__ int wavecnt[16][MAXIT + 1];
    __shared__ int binbase[MAXIT + 1];
    const size_t ch = (size_t)b * SCH + s;
    const int c = conv_ws[ch];
    int rw = 0;
#pragma unroll
    for (int v = 0; v <= MAXIT; ++v) {
        ull bal = __ballot(c == v);
        if (l == 0) wavecnt[w][v] = (int)__popcll(bal);
        if (c == v) rw = (int)__popcll(bal & ((1ull << l) - 1ull));
    }
    __syncthreads();
    if (s == 0) {
        int acc = 0;
        for (int v = 0; v <= MAXIT; ++v) {
            int t = 0;
            for (int w2 = 0; w2 < 16; ++w2) t += wavecnt[w2][v];
            binbase[v] = acc;
            acc += t;
        }
    }
    __syncthreads();
    int pos = binbase[c] + rw;
    for (int w2 = 0; w2 < w; ++w2) pos += wavecnt[w2][c];

    float* __restrict__ C  = out;                              // (B,S,3)
    float* __restrict__ I1 = out + (size_t)BATCH * SCH * 3;    // (B,S)
    float* __restrict__ I2 = I1 + (size_t)BATCH * SCH;         // (B,S,K)
    const size_t o = (size_t)b * SCH + pos;
    C[o * 3 + 0] = pts_ws[ch * 3 + 0];
    C[o * 3 + 1] = pts_ws[ch * 3 + 1];
    C[o * 3 + 2] = pts_ws[ch * 3 + 2];
    I1[o] = (float)idx_ws[ch];
#pragma unroll
    for (int k = 0; k < KNN; ++k) I2[o * KNN + k] = (float)grp_ws[ch * KNN + k];
}

extern "C" void kernel_launch(void* const* d_in, const int* in_sizes, int n_in,
                              void* d_out, int out_size, void* d_ws, size_t ws_size,
                              hipStream_t stream) {
    const float* xyz    = (const float*)d_in[0];  // (8,8192,3) f32
    const float* center = (const float*)d_in[1];  // (8,1024,3) f32
    const int*   idx_in = (const int*)d_in[2];    // (8,1024)   i32
    float* out = (float*)d_out;

    // workspace layout (~3.6 MB)
    char* wp = (char*)d_ws;
    vf4* pc4     = (vf4*)wp;  wp += (size_t)BATCH * NPTS * sizeof(vf4);   // 1 MB
    vf4* sortedP = (vf4*)wp;  wp += (size_t)BATCH * NPTS * sizeof(vf4);   // 1 MB
    vf4* bC      = (vf4*)wp;  wp += (size_t)BATCH * NGRP * sizeof(vf4);   // 16 KB
    vf4* bH      = (vf4*)wp;  wp += (size_t)BATCH * NGRP * sizeof(vf4);   // 16 KB
    int* counts  = (int*)wp;  wp += (size_t)BATCH * NCELL * 4;            // 128 KB
    int* cursor  = (int*)wp;  wp += (size_t)BATCH * NCELL * 4;            // 128 KB
    float* pts_ws = (float*)wp; wp += (size_t)BATCH * SCH * 3 * 4;
    int*   idx_ws = (int*)wp;   wp += (size_t)BATCH * SCH * 4;
    int*   grp_ws = (int*)wp;   wp += (size_t)BATCH * SCH * KNN * 4;      // 1 MB
    int*   conv_ws = (int*)wp;

    hipMemsetAsync(counts, 0, (size_t)BATCH * NCELL * 4, stream);
    prep_kernel<<<(BATCH * NPTS + 255) / 256, 256, 0, stream>>>(xyz, pc4, counts);
    scan_kernel<<<BATCH, 1024, 0, stream>>>(counts, cursor);
    scatter_kernel<<<(BATCH * NPTS + 255) / 256, 256, 0, stream>>>(pc4, cursor, sortedP);
    bbox_kernel<<<(BATCH * NGRP * 64) / 256, 256, 0, stream>>>(sortedP, bC, bH);

    const int chains = BATCH * SCH;                 // 8192 waves, 1 per chain
    refine_kernel<<<chains * 64 / 256, 256, 0, stream>>>(
        pc4, sortedP, bC, bH, center, idx_in, pts_ws, idx_ws, grp_ws, conv_ws);
    order_kernel<<<BATCH, SCH, 0, stream>>>(pts_ws, idx_ws, grp_ws, conv_ws, out);
}

// Round 9
// 240.639 us; speedup vs baseline: 1.6353x; 1.0572x over previous
//
#include <hip/hip_runtime.h>
#include <stdint.h>

#define BATCH   8
#define NPTS    8192
#define SCH     1024
#define KNN     32
#define TOPC    5
#define MAXIT   16
#define NCELL   4096     // 16^3 morton cells
#define NGRP    128      // groups of 64 per batch

typedef unsigned long long ull;
typedef float vf2 __attribute__((ext_vector_type(2)));
typedef float vf4 __attribute__((ext_vector_type(4)));

// sentinel: unpacks to +inf d2, never enters top-32
#define SENTKEY ((((ull)0x7F800000u) << 13) | 0x1FFFull)

// ---------------------------------------------------------------------------
// Exact d2: separate mul/add roundings (no FMA), order ((dx2+dy2)+dz2) = numpy.
// ---------------------------------------------------------------------------
__device__ __forceinline__ float d2_exact(vf4 q, vf4 p) {
#pragma clang fp contract(off)
    vf2 d = q.xy - p.xy;
    vf2 s = d * d;
    float dz = q.z - p.z;
    float sz = dz * dz;
    return (s.x + s.y) + sz;
}

__device__ __forceinline__ void insert_top4(ull key, ull& k0, ull& k1, ull& k2,
                                            ull& k3, float& th) {
    if (key < k3) {
        k3 = key;
        { bool c = k3 < k2; ull mn = c ? k3 : k2, mx = c ? k2 : k3; k2 = mn; k3 = mx; }
        { bool c = k2 < k1; ull mn = c ? k2 : k1, mx = c ? k1 : k2; k1 = mn; k2 = mx; }
        { bool c = k1 < k0; ull mn = c ? k1 : k0, mx = c ? k0 : k1; k0 = mn; k1 = mx; }
        th = __uint_as_float((uint32_t)(k3 >> 13));
    }
}

__device__ __forceinline__ ull wave_min_u64(ull k) {
#pragma unroll
    for (int off = 32; off; off >>= 1) {
        ull o = (ull)__shfl_xor((unsigned long long)k, off, 64);
        k = o < k ? o : k;
    }
    return k;
}

// conservative (under-estimated) squared min distance from q to group bbox
__device__ __forceinline__ float bbox_mind2(vf4 q, vf4 c, vf4 h) {
    float dx = fmaxf(fabsf(q.x - c.x) - h.x, 0.f);
    float dy = fmaxf(fabsf(q.y - c.y) - h.y, 0.f);
    float dz = fmaxf(fabsf(q.z - c.z) - h.z, 0.f);
    return (dx * dx + dy * dy + dz * dz) * 0.9999f;
}

// bitonic helpers
__device__ __forceinline__ ull cx(ull v, int xl, bool keepmin) {
    ull o = (ull)__shfl_xor((unsigned long long)v, xl, 64);
    return ((v < o) == keepmin) ? v : o;
}
__device__ __forceinline__ void cswap(ull& a, ull& b, bool up) {
    bool lt = a < b;
    ull mn = lt ? a : b, mx = lt ? b : a;
    a = up ? mn : mx;
    b = up ? mx : mn;
}

// morton cell id from point (16^3 over [-4,4], clamped)
__device__ __forceinline__ int cell_of(float x, float y, float z) {
    int cxi = min(15, max(0, (int)floorf((x + 4.0f) * 2.0f)));
    int cyi = min(15, max(0, (int)floorf((y + 4.0f) * 2.0f)));
    int czi = min(15, max(0, (int)floorf((z + 4.0f) * 2.0f)));
    uint32_t sx = (cxi & 1) | ((cxi & 2) << 2) | ((cxi & 4) << 4) | ((cxi & 8) << 6);
    uint32_t sy = (cyi & 1) | ((cyi & 2) << 2) | ((cyi & 4) << 4) | ((cyi & 8) << 6);
    uint32_t sz = (czi & 1) | ((czi & 2) << 2) | ((czi & 4) << 4) | ((czi & 8) << 6);
    return (int)(sx | (sy << 1) | (sz << 2));
}

// ---------------------------------------------------------------------------
// Rare fallback: exact serial extraction over the scanned groups (masked).
// ---------------------------------------------------------------------------
__device__ __attribute__((noinline)) int serial_topk_masked(
    const vf4* __restrict__ Psort, vf4 q, int lane, ull sm0, ull sm1) {
    ull k0 = SENTKEY, k1 = SENTKEY, k2 = SENTKEY, k3 = SENTKEY;
    int s0 = 0, s1 = 0, s2 = 0, s3 = 0;
    float th = __builtin_inff();
    for (int gid = 0; gid < NGRP; ++gid) {
        bool sel = (gid < 64) ? ((sm0 >> gid) & 1ull) : ((sm1 >> (gid - 64)) & 1ull);
        if (!sel) continue;
        vf4 p = Psort[(gid << 6) + lane];
        float d2 = d2_exact(q, p);
        uint32_t oi = __float_as_uint(p.w);
        ull key = ((ull)__float_as_uint(d2) << 13) | oi;
        if (d2 <= th && key < k3) {
            k3 = key; s3 = gid;
            if (k3 < k2) { ull t = k2; k2 = k3; k3 = t; int ts = s2; s2 = s3; s3 = ts; }
            if (k2 < k1) { ull t = k1; k1 = k2; k2 = t; int ts = s1; s1 = s2; s2 = ts; }
            if (k1 < k0) { ull t = k0; k0 = k1; k1 = t; int ts = s0; s0 = s1; s1 = ts; }
            th = __uint_as_float((uint32_t)(k3 >> 13));
        }
    }
    ull em0 = 0ull, em1 = 0ull;
    int cnt = 4, my_ind = 0;
    for (int r = 0; r < KNN; ++r) {
        ull gmin = wave_min_u64(k0);
        int widx = (int)(gmin & 0x1FFFull);
        if (lane == r) my_ind = widx;
        if (k0 == gmin) {
            int g = s0;
            if (g < 64) em0 |= 1ull << g; else em1 |= 1ull << (g - 64);
            k0 = k1; k1 = k2; k2 = k3; k3 = SENTKEY;
            s0 = s1; s1 = s2; s2 = s3;
            if (--cnt == 0) {
                k0 = k1 = k2 = k3 = SENTKEY;
                float th2 = __builtin_inff();
                for (int gid = 0; gid < NGRP; ++gid) {
                    bool sel = (gid < 64) ? ((sm0 >> gid) & 1ull)
                                          : ((sm1 >> (gid - 64)) & 1ull);
                    bool ex = (gid < 64) ? ((em0 >> gid) & 1ull)
                                         : ((em1 >> (gid - 64)) & 1ull);
                    if (!sel || ex) continue;
                    vf4 p = Psort[(gid << 6) + lane];
                    float d2 = d2_exact(q, p);
                    uint32_t oi = __float_as_uint(p.w);
                    ull key = ((ull)__float_as_uint(d2) << 13) | oi;
                    if (d2 <= th2 && key < k3) {
                        k3 = key; s3 = gid;
                        if (k3 < k2) { ull t = k2; k2 = k3; k3 = t; int ts = s2; s2 = s3; s3 = ts; }
                        if (k2 < k1) { ull t = k1; k1 = k2; k2 = t; int ts = s1; s1 = s2; s2 = ts; }
                        if (k1 < k0) { ull t = k0; k0 = k1; k1 = t; int ts = s0; s0 = s1; s1 = ts; }
                        th2 = __uint_as_float((uint32_t)(k3 >> 13));
                    }
                }
                cnt = 4;
            }
        }
    }
    return my_ind;
}

// ---------------------------------------------------------------------------
// Split parallel build (measured ~32 us vs ~75 us for the 8-block fused build)
// ---------------------------------------------------------------------------
__global__ __launch_bounds__(256) void prep_kernel(const float* __restrict__ xyz,
                                                   vf4* __restrict__ pc4,
                                                   int* __restrict__ counts) {
    int i = (int)(blockIdx.x * blockDim.x + threadIdx.x);
    if (i >= BATCH * NPTS) return;
    vf4 v;
    v.x = xyz[(size_t)i * 3 + 0];
    v.y = xyz[(size_t)i * 3 + 1];
    v.z = xyz[(size_t)i * 3 + 2];
    v.w = 0.f;
    pc4[i] = v;
    int b = i >> 13;
    atomicAdd(&counts[b * NCELL + cell_of(v.x, v.y, v.z)], 1);
}

__global__ __launch_bounds__(1024) void scan_kernel(const int* __restrict__ counts,
                                                    int* __restrict__ cursor) {
    int b = (int)blockIdx.x, tid = (int)threadIdx.x;
    __shared__ int part[1024];
    int base = b * NCELL + tid * 4;
    int v0 = counts[base], v1 = counts[base + 1], v2 = counts[base + 2], v3 = counts[base + 3];
    int s = v0 + v1 + v2 + v3;
    part[tid] = s;
    __syncthreads();
    for (int off = 1; off < 1024; off <<= 1) {
        int t = (tid >= off) ? part[tid - off] : 0;
        __syncthreads();
        part[tid] += t;
        __syncthreads();
    }
    int excl = part[tid] - s;
    cursor[base] = excl;
    cursor[base + 1] = excl + v0;
    cursor[base + 2] = excl + v0 + v1;
    cursor[base + 3] = excl + v0 + v1 + v2;
}

__global__ __launch_bounds__(256) void scatter_kernel(const vf4* __restrict__ pc4,
                                                      int* __restrict__ cursor,
                                                      vf4* __restrict__ sortedP) {
    int i = (int)(blockIdx.x * blockDim.x + threadIdx.x);
    if (i >= BATCH * NPTS) return;
    vf4 v = pc4[i];
    int b = i >> 13, pi = i & (NPTS - 1);
    int c = cell_of(v.x, v.y, v.z);
    int pos = atomicAdd(&cursor[b * NCELL + c], 1);
    v.w = __uint_as_float((uint32_t)pi);
    sortedP[((size_t)b << 13) + pos] = v;
}

__global__ __launch_bounds__(256) void bbox_kernel(const vf4* __restrict__ sortedP,
                                                   vf4* __restrict__ bC,
                                                   vf4* __restrict__ bH) {
    int g = (int)((blockIdx.x * blockDim.x + threadIdx.x) >> 6);  // 0..B*NGRP-1
    int lane = (int)(threadIdx.x & 63);
    vf4 p = sortedP[((size_t)g << 6) + lane];
    float mnx = p.x, mxx = p.x, mny = p.y, mxy = p.y, mnz = p.z, mxz = p.z;
#pragma unroll
    for (int off = 32; off; off >>= 1) {
        mnx = fminf(mnx, __shfl_xor(mnx, off, 64));
        mxx = fmaxf(mxx, __shfl_xor(mxx, off, 64));
        mny = fminf(mny, __shfl_xor(mny, off, 64));
        mxy = fmaxf(mxy, __shfl_xor(mxy, off, 64));
        mnz = fminf(mnz, __shfl_xor(mnz, off, 64));
        mxz = fmaxf(mxz, __shfl_xor(mxz, off, 64));
    }
    if (lane == 0) {
        vf4 cc, hh;
        cc.x = (mnx + mxx) * 0.5f; cc.y = (mny + mxy) * 0.5f;
        cc.z = (mnz + mxz) * 0.5f; cc.w = 0.f;
        hh.x = (mxx - mnx) * 0.5f; hh.y = (mxy - mny) * 0.5f;
        hh.z = (mxz - mnz) * 0.5f; hh.w = 0.f;
        bC[g] = cc;
        bH[g] = hh;
    }
}

// ---------------------------------------------------------------------------
// Main refine — r6 config verbatim: __launch_bounds__(256,4) => VGPR capped
// at 64 => 8 waves/SIMD. pf[8] partially spills to scratch; measured FASTER
// than spill-free at 6-7 waves/SIMD (r8). Do not "fix" the spill.
// ---------------------------------------------------------------------------
__global__ __launch_bounds__(256, 4) void refine_kernel(
    const vf4* __restrict__ pc4, const vf4* __restrict__ sortedP,
    const vf4* __restrict__ bC, const vf4* __restrict__ bH,
    const float* __restrict__ center, const int* __restrict__ idx_in,
    float* __restrict__ pts_ws, int* __restrict__ idx_ws,
    int* __restrict__ grp_ws, int* __restrict__ conv_ws) {
    const int wv = (int)((blockIdx.x * blockDim.x + threadIdx.x) >> 6);
    const int lane = (int)(threadIdx.x & 63);
    const int w = (int)(threadIdx.x >> 6);
    const int b = wv >> 10;
    const vf4* __restrict__ Porig = pc4 + ((size_t)b << 13);
    const vf4* __restrict__ Psort = sortedP + ((size_t)b << 13);

    __shared__ vf4 nbh[4][KNN];

    // bboxes are loop-invariant: lane owns groups (lane) and (64+lane)
    const int b128 = b << 7;
    const vf4 c0 = bC[b128 + lane], h0 = bH[b128 + lane];
    const vf4 c1 = bC[b128 + 64 + lane], h1 = bH[b128 + 64 + lane];

    const size_t ch = (size_t)wv;
    vf4 q;
    q.x = center[ch * 3 + 0];
    q.y = center[ch * 3 + 1];
    q.z = center[ch * 3 + 2];
    q.w = 0.f;
    int qidx = idx_in[ch];

    int conv = MAXIT;
    int my_ind = 0;

    for (int it = 0;; ++it) {
        // ---- per-lane bbox min-d2 for its 2 groups ----
        const float m0 = bbox_mind2(q, c0, h0);
        const float m1 = bbox_mind2(q, c1, h1);
        // 32-bit quantized keys: (mind2 truncated to 25 bits) | gid. Monotone
        // truncation; a near-tie mis-pick only loosens B, never unsound.
        const uint32_t q0k = (__float_as_uint(m0) & 0xFFFFFF80u) | (uint32_t)lane;
        const uint32_t q1k = (__float_as_uint(m1) & 0xFFFFFF80u) | (uint32_t)(64 + lane);

        // ---- two smallest via one 6-step 32-bit butterfly ----
        uint32_t s1 = q0k < q1k ? q0k : q1k, s2 = q0k < q1k ? q1k : q0k;
#pragma unroll
        for (int off = 32; off; off >>= 1) {
            uint32_t o1 = (uint32_t)__shfl_xor((int)s1, off, 64);
            uint32_t o2 = (uint32_t)__shfl_xor((int)s2, off, 64);
            uint32_t hi = s1 > o1 ? s1 : o1;
            uint32_t lo2 = s2 < o2 ? s2 : o2;
            s1 = s1 < o1 ? s1 : o1;
            s2 = hi < lo2 ? hi : lo2;
        }
        const int g1 = (int)(s1 & 127u);
        const int g2 = (int)(s2 & 127u);

        // ---- scan the 2 nearest groups (loads issued together) ----
        ull k0 = SENTKEY, k1 = SENTKEY, k2 = SENTKEY, k3 = SENTKEY;
        float th = __builtin_inff();
        {
            const vf4 p1 = Psort[(g1 << 6) + lane];
            const vf4 p2 = Psort[(g2 << 6) + lane];
            float d2a = d2_exact(q, p1);
            insert_top4(((ull)__float_as_uint(d2a) << 13) | __float_as_uint(p1.w),
                        k0, k1, k2, k3, th);
            float d2b = d2_exact(q, p2);
            if (d2b <= th)
                insert_top4(((ull)__float_as_uint(d2b) << 13) | __float_as_uint(p2.w),
                            k0, k1, k2, k3, th);
        }

        // ---- sound bound B: max of 32 distinct actual candidate d2's ----
        // (32 pairwise-mins are 32 distinct candidates; max >= 32nd of union)
        uint32_t tb;
        {
            ull t = k0;
            ull o = (ull)__shfl_xor((unsigned long long)t, 32, 64);
            t = o < t ? o : t;
            tb = (uint32_t)(t >> 13);   // d2 bits (nonneg float: bit order = fp order)
#pragma unroll
            for (int off = 32; off; off >>= 1) {
                uint32_t ob = (uint32_t)__shfl_xor((int)tb, off, 64);
                tb = ob > tb ? ob : tb;
            }
        }
        const float Bd = __uint_as_float(tb);

        // ---- one ballot selects every group that can hold a top-32 point ----
        ull sm0 = __ballot(m0 <= Bd);
        ull sm1 = __ballot(m1 <= Bd);
        ull fb0 = sm0, fb1 = sm1;   // scanned-set for fallback
        if (g1 < 64) fb0 |= 1ull << g1; else fb1 |= 1ull << (g1 - 64);
        if (g2 < 64) fb0 |= 1ull << g2; else fb1 |= 1ull << (g2 - 64);
        if (g1 < 64) sm0 &= ~(1ull << g1); else sm1 &= ~(1ull << (g1 - 64));
        if (g2 < 64) sm0 &= ~(1ull << g2); else sm1 &= ~(1ull << (g2 - 64));

        // ---- deep-prefetch masked scan: batches of 8 loads in flight ----
        {
            ull mm0 = sm0, mm1 = sm1;
            while (mm0 | mm1) {
                int gl[8];
                vf4 pf[8];
#pragma unroll
                for (int j = 0; j < 8; ++j) {
                    int gg = -1;
                    if (mm0)      { gg = (int)__builtin_ctzll(mm0); mm0 &= mm0 - 1; }
                    else if (mm1) { gg = 64 + (int)__builtin_ctzll(mm1); mm1 &= mm1 - 1; }
                    gl[j] = gg;
                    if (gg >= 0) pf[j] = Psort[(gg << 6) + lane];
                }
#pragma unroll
                for (int j = 0; j < 8; ++j) {
                    if (gl[j] >= 0) {
                        const float d2 = d2_exact(q, pf[j]);
                        if (d2 <= th)
                            insert_top4(((ull)__float_as_uint(d2) << 13) |
                                            __float_as_uint(pf[j].w),
                                        k0, k1, k2, k3, th);
                    }
                }
            }
        }
        const ull prek3 = k3;

        // ---- wave bitonic sort of 256 candidates (sentinel-padded) ----
        const bool odd = (lane & 1) != 0;
        ull a0 = odd ? k3 : k0;
        ull a1 = odd ? k2 : k1;
        ull a2 = odd ? k1 : k2;
        ull a3 = odd ? k0 : k3;
#pragma unroll
        for (int kk = 8; kk <= 256; kk <<= 1) {
            const bool up = (lane & (kk >> 2)) == 0;
#pragma unroll
            for (int d = kk >> 1; d >= 4; d >>= 1) {
                const int xl = d >> 2;
                const bool keepmin = (up == ((lane & xl) == 0));
                a0 = cx(a0, xl, keepmin);
                a1 = cx(a1, xl, keepmin);
                a2 = cx(a2, xl, keepmin);
                a3 = cx(a3, xl, keepmin);
            }
            cswap(a0, a2, up); cswap(a1, a3, up);
            cswap(a0, a1, up); cswap(a2, a3, up);
        }
        // rank r lives at lane r>>2, reg r&3; tau = rank-31 key
        const ull tau = (ull)__shfl((unsigned long long)a3, 7, 64);
        const ull bad = __ballot(prek3 < tau);
        if (bad != 0ull) {
            my_ind = serial_topk_masked(Psort, q, lane, fb0, fb1);
        } else {
            const int src = lane >> 2;
            const uint32_t lo0 = (uint32_t)__shfl((int)(uint32_t)a0, src, 64);
            const uint32_t lo1 = (uint32_t)__shfl((int)(uint32_t)a1, src, 64);
            const uint32_t lo2 = (uint32_t)__shfl((int)(uint32_t)a2, src, 64);
            const uint32_t lo3 = (uint32_t)__shfl((int)(uint32_t)a3, src, 64);
            const int sel = lane & 3;
            uint32_t lo = (sel == 0) ? lo0 : (sel == 1) ? lo1 : (sel == 2) ? lo2 : lo3;
            my_ind = (int)(lo & 0x1FFFu);
        }

        if (it == MAXIT) break;  // final step's ind recorded; conv stays MAXIT

        // ---- centroid: stage 32 ordered neighbors to LDS, sequential fold ----
        vf4 myp = q;
        if (lane < KNN) {
            myp = Porig[my_ind];
            nbh[w][lane] = myp;
        }
        __asm__ volatile("s_waitcnt lgkmcnt(0)" ::: "memory");
        float sx = 0.f, sy = 0.f, sz = 0.f;
#pragma unroll
        for (int j = 0; j < KNN; ++j) {
            vf4 pj = nbh[w][j];
            sx = __fadd_rn(sx, pj.x);
            sy = __fadd_rn(sy, pj.y);
            sz = __fadd_rn(sz, pj.z);
        }
        const float gx = __fmul_rn(sx, 0.03125f);
        const float gy = __fmul_rn(sy, 0.03125f);
        const float gz = __fmul_rn(sz, 0.03125f);

        // ---- per-neighbor distance to centroid (post-sqrt ordering) ----
        float dj = __builtin_inff();
        if (lane < KNN) {
            const float dx = __fsub_rn(myp.x, gx);
            const float dy = __fsub_rn(myp.y, gy);
            const float dz = __fsub_rn(myp.z, gz);
            dj = sqrtf(__fadd_rn(__fadd_rn(__fmul_rn(dx, dx), __fmul_rn(dy, dy)),
                                 __fmul_rn(dz, dz)));
        }
        const uint32_t db = __float_as_uint(dj);  // nonneg: bit order == fp order
        const uint32_t d0 = (uint32_t)__shfl((int)db, 0, 64);
        const ull bal = __ballot(db < d0);
        if (__popcll(bal) <= TOPC - 1) { conv = it; break; }

        // move target: lexicographic argmin of (dist, j)
        uint32_t m2 = db;
#pragma unroll
        for (int off = 32; off; off >>= 1) {
            uint32_t o = (uint32_t)__shfl_xor((int)m2, off, 64);
            m2 = o < m2 ? o : m2;
        }
        const ull balm = __ballot(db == m2);
        const int jm = __ffsll((unsigned long long)balm) - 1;
        const int nidx = __shfl(my_ind, jm, 64);
        qidx = nidx;
        q = Porig[nidx];
        q.w = 0.f;
    }

    if (lane < KNN) grp_ws[ch * KNN + lane] = my_ind;
    if (lane == 0) {
        pts_ws[ch * 3 + 0] = q.x;
        pts_ws[ch * 3 + 1] = q.y;
        pts_ws[ch * 3 + 2] = q.z;
        idx_ws[ch] = qidx;
        conv_ws[ch] = conv;
    }
}

// ---------------------------------------------------------------------------
// Order: stable rank by (conv, s) via 17-bin counting
// ---------------------------------------------------------------------------
__global__ __launch_bounds__(1024) void order_kernel(
    const float* __restrict__ pts_ws, const int* __restrict__ idx_ws,
    const int* __restrict__ grp_ws, const int* __restrict__ conv_ws,
    float* __restrict__ out) {
    const int b = (int)blockIdx.x;
    const int s = (int)threadIdx.x;
    const int w = s >> 6, l = s & 63;
    __shared__ int wavecnt[16][MAXIT + 1];
    __shared__ int binbase[MAXIT + 1];
    const size_t ch = (size_t)b * SCH + s;
    const int c = conv_ws[ch];
    int rw = 0;
#pragma unroll
    for (int v = 0; v <= MAXIT; ++v) {
        ull bal = __ballot(c == v);
        if (l == 0) wavecnt[w][v] = (int)__popcll(bal);
        if (c == v) rw = (int)__popcll(bal & ((1ull << l) - 1ull));
    }
    __syncthreads();
    if (s == 0) {
        int acc = 0;
        for (int v = 0; v <= MAXIT; ++v) {
            int t = 0;
            for (int w2 = 0; w2 < 16; ++w2) t += wavecnt[w2][v];
            binbase[v] = acc;
            acc += t;
        }
    }
    __syncthreads();
    int pos = binbase[c] + rw;
    for (int w2 = 0; w2 < w; ++w2) pos += wavecnt[w2][c];

    float* __restrict__ C  = out;                              // (B,S,3)
    float* __restrict__ I1 = out + (size_t)BATCH * SCH * 3;    // (B,S)
    float* __restrict__ I2 = I1 + (size_t)BATCH * SCH;         // (B,S,K)
    const size_t o = (size_t)b * SCH + pos;
    C[o * 3 + 0] = pts_ws[ch * 3 + 0];
    C[o * 3 + 1] = pts_ws[ch * 3 + 1];
    C[o * 3 + 2] = pts_ws[ch * 3 + 2];
    I1[o] = (float)idx_ws[ch];
#pragma unroll
    for (int k = 0; k < KNN; ++k) I2[o * KNN + k] = (float)grp_ws[ch * KNN + k];
}

extern "C" void kernel_launch(void* const* d_in, const int* in_sizes, int n_in,
                              void* d_out, int out_size, void* d_ws, size_t ws_size,
                              hipStream_t stream) {
    const float* xyz    = (const float*)d_in[0];  // (8,8192,3) f32
    const float* center = (const float*)d_in[1];  // (8,1024,3) f32
    const int*   idx_in = (const int*)d_in[2];    // (8,1024)   i32
    float* out = (float*)d_out;

    // workspace layout (~3.6 MB)
    char* wp = (char*)d_ws;
    vf4* pc4     = (vf4*)wp;  wp += (size_t)BATCH * NPTS * sizeof(vf4);   // 1 MB
    vf4* sortedP = (vf4*)wp;  wp += (size_t)BATCH * NPTS * sizeof(vf4);   // 1 MB
    vf4* bC      = (vf4*)wp;  wp += (size_t)BATCH * NGRP * sizeof(vf4);   // 16 KB
    vf4* bH      = (vf4*)wp;  wp += (size_t)BATCH * NGRP * sizeof(vf4);   // 16 KB
    int* counts  = (int*)wp;  wp += (size_t)BATCH * NCELL * 4;            // 128 KB
    int* cursor  = (int*)wp;  wp += (size_t)BATCH * NCELL * 4;            // 128 KB
    float* pts_ws = (float*)wp; wp += (size_t)BATCH * SCH * 3 * 4;
    int*   idx_ws = (int*)wp;   wp += (size_t)BATCH * SCH * 4;
    int*   grp_ws = (int*)wp;   wp += (size_t)BATCH * SCH * KNN * 4;      // 1 MB
    int*   conv_ws = (int*)wp;

    hipMemsetAsync(counts, 0, (size_t)BATCH * NCELL * 4, stream);
    prep_kernel<<<(BATCH * NPTS + 255) / 256, 256, 0, stream>>>(xyz, pc4, counts);
    scan_kernel<<<BATCH, 1024, 0, stream>>>(counts, cursor);
    scatter_kernel<<<(BATCH * NPTS + 255) / 256, 256, 0, stream>>>(pc4, cursor, sortedP);
    bbox_kernel<<<(BATCH * NGRP * 64) / 256, 256, 0, stream>>>(sortedP, bC, bH);

    const int chains = BATCH * SCH;                 // 8192 waves, 1 per chain
    refine_kernel<<<chains * 64 / 256, 256, 0, stream>>>(
        pc4, sortedP, bC, bH, center, idx_in, pts_ws, idx_ws, grp_ws, conv_ws);
    order_kernel<<<BATCH, SCH, 0, stream>>>(pts_ws, idx_ws, grp_ws, conv_ws, out);
}